// Round 1
// baseline (890.854 us; speedup 1.0000x reference)
//
#include <hip/hip_runtime.h>
#include <hip/hip_bf16.h>
#include <cstdint>
#include <cstddef>

// Problem constants (fixed by the reference)
#define NB 8
#define NT 256
#define NU 64
#define DJ 512      // JOINT_D
#define DV 1024     // VOCAB
#define DK 256      // ENC_D == PRED_D

typedef __attribute__((ext_vector_type(8))) short short8;
typedef __attribute__((ext_vector_type(4))) float floatx4;

__device__ __forceinline__ unsigned short f2bf(float x) {
    unsigned int u = __float_as_uint(x);
    u += 0x7fffu + ((u >> 16) & 1u);   // round-to-nearest-even
    return (unsigned short)(u >> 16);
}

// ---------------------------------------------------------------------------
// Kernel 1: enc_proj = enc @ W1[:, :256]^T + b1   (2048 x 512)
//           dec_proj = dec @ W1[:, 256:]^T        (512  x 512)
// Classic 64x64 fp32 LDS-tiled GEMM, 256 threads, 4x4 per thread.
// grid = (8, 40): mt 0..31 -> enc rows, mt 32..39 -> dec rows.
// ---------------------------------------------------------------------------
__global__ __launch_bounds__(256) void stage1_gemm(
    const float* __restrict__ enc, const float* __restrict__ dec,
    const float* __restrict__ W1, const float* __restrict__ b1,
    float* __restrict__ enc_proj, float* __restrict__ dec_proj)
{
    __shared__ float As[64][17];
    __shared__ float Bs[16][65];

    const int n0 = blockIdx.x * 64;
    const int m0 = blockIdx.y * 64;
    const bool is_enc = (m0 < NB * NT);
    const float* A = is_enc ? enc : dec;
    const int arow0 = is_enc ? m0 : (m0 - NB * NT);
    const int koff  = is_enc ? 0 : DK;
    float* C = is_enc ? enc_proj : dec_proj;

    const int tid = threadIdx.x;
    const int kk = tid & 15;      // k index for staging
    const int grp = tid >> 4;     // 0..15
    const int tx = tid & 15;      // output col group
    const int ty = tid >> 4;      // output row group

    float acc[4][4] = {};

    for (int k0 = 0; k0 < DK; k0 += 16) {
        #pragma unroll
        for (int g = 0; g < 4; g++) {
            As[grp + g * 16][kk] = A[(size_t)(arow0 + grp + g * 16) * DK + k0 + kk];
            Bs[kk][grp + g * 16] = W1[(size_t)(n0 + grp + g * 16) * DJ + koff + k0 + kk];
        }
        __syncthreads();
        #pragma unroll
        for (int k = 0; k < 16; k++) {
            float av[4], bv[4];
            #pragma unroll
            for (int i = 0; i < 4; i++) av[i] = As[ty * 4 + i][k];
            #pragma unroll
            for (int j = 0; j < 4; j++) bv[j] = Bs[k][tx * 4 + j];
            #pragma unroll
            for (int i = 0; i < 4; i++)
                #pragma unroll
                for (int j = 0; j < 4; j++)
                    acc[i][j] = fmaf(av[i], bv[j], acc[i][j]);
        }
        __syncthreads();
    }

    float4 bias = make_float4(0.f, 0.f, 0.f, 0.f);
    if (is_enc) bias = *(const float4*)&b1[n0 + tx * 4];
    #pragma unroll
    for (int i = 0; i < 4; i++) {
        const int row = arow0 + ty * 4 + i;
        float4 v;
        v.x = acc[i][0] + bias.x;
        v.y = acc[i][1] + bias.y;
        v.z = acc[i][2] + bias.z;
        v.w = acc[i][3] + bias.w;
        *(float4*)&C[(size_t)row * DJ + n0 + tx * 4] = v;
    }
}

// ---------------------------------------------------------------------------
// Kernel 2: W2 fp32 -> bf16 (1024 x 512), exact grid 512 x 256 x 4 elems
// ---------------------------------------------------------------------------
__global__ __launch_bounds__(256) void convert_w2(
    const float* __restrict__ W2, unsigned short* __restrict__ W2b)
{
    const int i = (blockIdx.x * 256 + threadIdx.x) * 4;
    float4 v = *(const float4*)(W2 + i);
    ushort4 o;
    o.x = f2bf(v.x); o.y = f2bf(v.y); o.z = f2bf(v.z); o.w = f2bf(v.w);
    *(ushort4*)(W2b + i) = o;
}

// ---------------------------------------------------------------------------
// Kernel 3: fused joint: h = tanh(enc_proj[b,t]+dec_proj[b,u]) -> bf16 LDS,
// logits = h @ W2^T + b2 via MFMA 16x16x32 bf16, fused log_softmax, store.
// One block per (b,t): 64 rows (u) x 1024 cols (v), K=512.
// 512 threads = 8 waves; wave w: all 64 rows x cols [w*128, w*128+128).
// MFMA 16x16x32 layouts (HW-verified m89/m120):
//   A: lane holds A[m=lane&15][k=(lane>>4)*8 + j]  (8 contiguous k -> b128)
//   B: lane holds B[k=(lane>>4)*8 + j][n=lane&15]  (W2 row-major fits: 8 contig j)
//   C: reg r -> row=(lane>>4)*4+r, col=lane&15
// LDS ha: 64 rows x 512 bf16, 16B chunks XOR-swizzled by (u&7) -> 2-way (free).
// ---------------------------------------------------------------------------
__global__ __launch_bounds__(512, 2) void joint_kernel(
    const float* __restrict__ enc_proj, const float* __restrict__ dec_proj,
    const unsigned short* __restrict__ W2b, const float* __restrict__ b2,
    float* __restrict__ out)
{
    __shared__ __align__(16) unsigned char smem[65536];
    unsigned short* ha = (unsigned short*)smem;   // [64][512], swizzled

    const int bt = blockIdx.x;            // b*256 + t
    const int b = bt >> 8;
    const int tid = threadIdx.x;

    // ---- Phase 1: h tile -> LDS (bf16) ----
    {
        const float e = enc_proj[(size_t)bt * DJ + tid];
        const float* dp = dec_proj + (size_t)(b * NU) * DJ + tid;
        const int chunk = tid >> 3;
        const int within = tid & 7;
        #pragma unroll 4
        for (int u = 0; u < NU; u++) {
            float x = e + dp[(size_t)u * DJ];
            float ex = __expf(2.0f * x);
            float h = 1.0f - 2.0f / (ex + 1.0f);     // tanh(x)
            ha[u * DJ + ((chunk ^ (u & 7)) << 3) + within] = f2bf(h);
        }
    }
    __syncthreads();

    const int w = tid >> 6;
    const int lane = tid & 63;
    const int q = lane >> 4;
    const int nn = lane & 15;
    const int nbase = w * 128;

    floatx4 acc[4][8];
    #pragma unroll
    for (int rt = 0; rt < 4; rt++)
        #pragma unroll
        for (int ct = 0; ct < 8; ct++)
            acc[rt][ct] = (floatx4){0.f, 0.f, 0.f, 0.f};

    // ---- Phase 2: K-loop, 16 steps of k=32 ----
    for (int ks = 0; ks < 16; ks++) {
        short8 av[4];
        #pragma unroll
        for (int rt = 0; rt < 4; rt++) {
            const int u = rt * 16 + nn;
            const int c = ((ks * 4 + q) ^ (u & 7)) << 3;
            av[rt] = *(const short8*)(ha + u * DJ + c);
        }
        short8 bv[8];
        #pragma unroll
        for (int ct = 0; ct < 8; ct++) {
            bv[ct] = *(const short8*)(W2b + (size_t)(nbase + ct * 16 + nn) * DJ + ks * 32 + q * 8);
        }
        #pragma unroll
        for (int rt = 0; rt < 4; rt++)
            #pragma unroll
            for (int ct = 0; ct < 8; ct++)
                acc[rt][ct] = __builtin_amdgcn_mfma_f32_16x16x32_bf16(
                    av[rt], bv[ct], acc[rt][ct], 0, 0, 0);
    }

    __syncthreads();   // ha dead from here; reuse smem for reductions

    float* wred     = (float*)smem;               // [64][8]
    float* rowmax_s = (float*)(smem + 2048);      // [64]
    float* rowoff_s = (float*)(smem + 2048 + 256);// [64]

    // add b2
    float b2v[8];
    #pragma unroll
    for (int ct = 0; ct < 8; ct++) b2v[ct] = b2[nbase + ct * 16 + nn];
    #pragma unroll
    for (int rt = 0; rt < 4; rt++)
        #pragma unroll
        for (int ct = 0; ct < 8; ct++)
            #pragma unroll
            for (int r = 0; r < 4; r++)
                acc[rt][ct][r] += b2v[ct];

    // per-row max: 8 regs -> 16-lane quad-group shuffle -> per-wave slot
    #pragma unroll
    for (int rt = 0; rt < 4; rt++) {
        #pragma unroll
        for (int r = 0; r < 4; r++) {
            float m = acc[rt][0][r];
            #pragma unroll
            for (int ct = 1; ct < 8; ct++) m = fmaxf(m, acc[rt][ct][r]);
            #pragma unroll
            for (int mk = 1; mk <= 8; mk <<= 1) m = fmaxf(m, __shfl_xor(m, mk, 64));
            if (nn == 0) wred[(rt * 16 + q * 4 + r) * 8 + w] = m;
        }
    }
    __syncthreads();
    if (tid < 64) {
        float m = wred[tid * 8];
        #pragma unroll
        for (int i = 1; i < 8; i++) m = fmaxf(m, wred[tid * 8 + i]);
        rowmax_s[tid] = m;
    }
    __syncthreads();

    // per-row sum of exp
    #pragma unroll
    for (int rt = 0; rt < 4; rt++) {
        #pragma unroll
        for (int r = 0; r < 4; r++) {
            const float rm = rowmax_s[rt * 16 + q * 4 + r];
            float s = 0.f;
            #pragma unroll
            for (int ct = 0; ct < 8; ct++) s += __expf(acc[rt][ct][r] - rm);
            #pragma unroll
            for (int mk = 1; mk <= 8; mk <<= 1) s += __shfl_xor(s, mk, 64);
            if (nn == 0) wred[(rt * 16 + q * 4 + r) * 8 + w] = s;
        }
    }
    __syncthreads();
    if (tid < 64) {
        float s = 0.f;
        #pragma unroll
        for (int i = 0; i < 8; i++) s += wred[tid * 8 + i];
        rowoff_s[tid] = rowmax_s[tid] + __logf(s);
    }
    __syncthreads();

    // store: out[bt*64 + u][v] = logit - (max + log(sum))
    float* outb = out + (size_t)bt * NU * DV;
    #pragma unroll
    for (int rt = 0; rt < 4; rt++) {
        #pragma unroll
        for (int r = 0; r < 4; r++) {
            const int u = rt * 16 + q * 4 + r;
            const float off = rowoff_s[u];
            #pragma unroll
            for (int ct = 0; ct < 8; ct++) {
                outb[(size_t)u * DV + nbase + ct * 16 + nn] = acc[rt][ct][r] - off;
            }
        }
    }
}

// ---------------------------------------------------------------------------
extern "C" void kernel_launch(void* const* d_in, const int* in_sizes, int n_in,
                              void* d_out, int out_size, void* d_ws, size_t ws_size,
                              hipStream_t stream) {
    const float* enc = (const float*)d_in[0];   // (8,256,256)
    const float* dec = (const float*)d_in[1];   // (8,64,256)
    const float* W1  = (const float*)d_in[2];   // (512,512)
    const float* b1  = (const float*)d_in[3];   // (512,)
    const float* W2  = (const float*)d_in[4];   // (1024,512)
    const float* b2  = (const float*)d_in[5];   // (1024,)
    float* out = (float*)d_out;                 // (8,256,64,1024)

    // workspace layout: enc_proj (2048x512 f32) | dec_proj (512x512 f32) | W2 bf16 (1024x512)
    float* enc_proj = (float*)d_ws;
    float* dec_proj = enc_proj + (size_t)(NB * NT) * DJ;
    unsigned short* W2b = (unsigned short*)(dec_proj + (size_t)DJ * DJ);

    dim3 g1(8, 40);
    stage1_gemm<<<g1, 256, 0, stream>>>(enc, dec, W1, b1, enc_proj, dec_proj);
    convert_w2<<<512, 256, 0, stream>>>(W2, W2b);
    joint_kernel<<<NB * NT, 512, 0, stream>>>(enc_proj, dec_proj, W2b, b2, out);
}